// Round 14
// baseline (5049.595 us; speedup 1.0000x reference)
//
#include <hip/hip_runtime.h>
#include <math.h>

#define VOCAB 8000
#define BATCH 128
#define TMAX  512
#define DIM   256
#define HID   128
#define G4    512     // 4*HID
#define NCOL  1024    // 2*G4 (both directions)

#define BARLDS() asm volatile("s_waitcnt lgkmcnt(0)\n\ts_barrier" ::: "memory")

// --- DPP quad-lane ops (R10: win over ds_bpermute __shfl) ---
__device__ __forceinline__ float dpp_xor1(float x) {   // [1,0,3,2] = 0xB1
  int r = __builtin_amdgcn_update_dpp(0, __builtin_bit_cast(int, x),
                                      0xB1, 0xF, 0xF, true);
  return __builtin_bit_cast(float, r);
}
__device__ __forceinline__ float dpp_xor2(float x) {   // [2,3,0,1] = 0x4E
  int r = __builtin_amdgcn_update_dpp(0, __builtin_bit_cast(int, x),
                                      0x4E, 0xF, 0xF, true);
  return __builtin_bit_cast(float, r);
}
__device__ __forceinline__ unsigned dpp_xor1u(unsigned x) {
  return (unsigned)__builtin_amdgcn_update_dpp(0, (int)x, 0xB1, 0xF, 0xF, true);
}
__device__ __forceinline__ unsigned dpp_xor2u(unsigned x) {
  return (unsigned)__builtin_amdgcn_update_dpp(0, (int)x, 0x4E, 0xF, 0xF, true);
}
__device__ __forceinline__ float dpp_bc0(float x) {
  int r = __builtin_amdgcn_update_dpp(0, __builtin_bit_cast(int, x),
                                      0x00, 0xF, 0xF, true);
  return __builtin_bit_cast(float, r);
}
__device__ __forceinline__ float dpp_bc1(float x) {
  int r = __builtin_amdgcn_update_dpp(0, __builtin_bit_cast(int, x),
                                      0x55, 0xF, 0xF, true);
  return __builtin_bit_cast(float, r);
}
__device__ __forceinline__ float dpp_bc2(float x) {
  int r = __builtin_amdgcn_update_dpp(0, __builtin_bit_cast(int, x),
                                      0xAA, 0xF, 0xF, true);
  return __builtin_bit_cast(float, r);
}
__device__ __forceinline__ float dpp_bc3(float x) {
  int r = __builtin_amdgcn_update_dpp(0, __builtin_bit_cast(int, x),
                                      0xFF, 0xF, 0xF, true);
  return __builtin_bit_cast(float, r);
}

// ---------------------------------------------------------------------------
// Kernel 1: embW[v][n] = emb[v,:] . W_ih_dir[n,:] + b_ih_dir[n] + b_hh_dir[n]
// 128x128 tile, 8x8 micro (fits default VGPR budget ~100 -- R13's 8x16 micro
// needed ~196 live regs and spilled, +70us). LDS DOUBLE-BUFFER: one barrier
// per k0-chunk (was 2), global->LDS stage of chunk k+1 overlaps MACs of k.
// ---------------------------------------------------------------------------
__global__ __launch_bounds__(256) void embw_gemm(
    const float* __restrict__ emb,
    const float* __restrict__ Wf, const float* __restrict__ Wb,
    const float* __restrict__ bihf, const float* __restrict__ bhhf,
    const float* __restrict__ bihb, const float* __restrict__ bhhb,
    float* __restrict__ embW) {
  __shared__ float As[2][32][132];   // k-major, padded; 2 buffers = 33.8 KB
  __shared__ float Bs[2][32][132];   //                            = 33.8 KB
  const int tid = threadIdx.x;
  const int m0 = blockIdx.x * 128;
  const int n0 = blockIdx.y * 128;
  const int tx = tid & 15, ty = tid >> 4;
  const int lrow = tid >> 1;            // 0..127
  const int lseg = (tid & 1) * 16;      // 0 or 16 (k offset)
  const float* Wsrc = (n0 < 512) ? Wf : Wb;
  const int nbase = (n0 < 512) ? n0 : (n0 - 512);
  const int gm = m0 + lrow;

  float acc[8][8];
  #pragma unroll
  for (int i = 0; i < 8; ++i)
    #pragma unroll
    for (int jj = 0; jj < 8; ++jj) acc[i][jj] = 0.f;

  float4 la[4], lb[4];
#define LOADT(K0)                                                         \
  { _Pragma("unroll")                                                     \
    for (int qq = 0; qq < 4; ++qq) {                                      \
      la[qq] = make_float4(0.f, 0.f, 0.f, 0.f);                           \
      if (gm < VOCAB)                                                     \
        la[qq] = *(const float4*)(emb + (size_t)gm * 256 + (K0) + lseg + 4 * qq); \
      lb[qq] = *(const float4*)(Wsrc + (size_t)(nbase + lrow) * 256 + (K0) + lseg + 4 * qq); \
    } }
#define STAGE(P)                                                          \
  { _Pragma("unroll")                                                     \
    for (int qq = 0; qq < 4; ++qq) {                                      \
      As[P][lseg + 4*qq + 0][lrow] = la[qq].x;                            \
      As[P][lseg + 4*qq + 1][lrow] = la[qq].y;                            \
      As[P][lseg + 4*qq + 2][lrow] = la[qq].z;                            \
      As[P][lseg + 4*qq + 3][lrow] = la[qq].w;                            \
      Bs[P][lseg + 4*qq + 0][lrow] = lb[qq].x;                            \
      Bs[P][lseg + 4*qq + 1][lrow] = lb[qq].y;                            \
      Bs[P][lseg + 4*qq + 2][lrow] = lb[qq].z;                            \
      Bs[P][lseg + 4*qq + 3][lrow] = lb[qq].w;                            \
    } }

  LOADT(0)
  STAGE(0)
  __syncthreads();

  #pragma unroll
  for (int it = 0; it < 8; ++it) {           // k0 = 32*it; p = it&1 (const)
    const int p = it & 1;
    if (it + 1 < 8) LOADT(32 * (it + 1))     // in flight under the MAC loop
    #pragma unroll
    for (int k = 0; k < 32; ++k) {
      float4 av0 = *(const float4*)&As[p][k][ty * 8];
      float4 av1 = *(const float4*)&As[p][k][ty * 8 + 4];
      float4 bv0 = *(const float4*)&Bs[p][k][tx * 4];
      float4 bv1 = *(const float4*)&Bs[p][k][64 + tx * 4];
      float a[8]  = {av0.x, av0.y, av0.z, av0.w, av1.x, av1.y, av1.z, av1.w};
      float bb[8] = {bv0.x, bv0.y, bv0.z, bv0.w, bv1.x, bv1.y, bv1.z, bv1.w};
      #pragma unroll
      for (int i = 0; i < 8; ++i)
        #pragma unroll
        for (int jj = 0; jj < 8; ++jj)
          acc[i][jj] += a[i] * bb[jj];
    }
    if (it + 1 < 8) STAGE(p ^ 1)             // write OTHER buffer: no WAR
    __syncthreads();                         // ONE barrier per chunk
  }
#undef STAGE
#undef LOADT

  float bias[8];
  #pragma unroll
  for (int jj = 0; jj < 8; ++jj) {
    int n = n0 + ((jj < 4) ? (tx * 4 + jj) : (64 + tx * 4 + (jj - 4)));
    bias[jj] = (n < 512) ? (bihf[n] + bhhf[n]) : (bihb[n - 512] + bhhb[n - 512]);
  }
  #pragma unroll
  for (int i = 0; i < 8; ++i) {
    int gmo = m0 + ty * 8 + i;
    if (gmo >= VOCAB) continue;
    float4 v0 = make_float4(acc[i][0] + bias[0], acc[i][1] + bias[1],
                            acc[i][2] + bias[2], acc[i][3] + bias[3]);
    float4 v1 = make_float4(acc[i][4] + bias[4], acc[i][5] + bias[5],
                            acc[i][6] + bias[6], acc[i][7] + bias[7]);
    *(float4*)(embW + (size_t)gmo * NCOL + n0 + tx * 4) = v0;
    *(float4*)(embW + (size_t)gmo * NCOL + n0 + 64 + tx * 4) = v1;
  }
}

// ---------------------------------------------------------------------------
// Kernel 2: masked LSTM recurrence -- R11/R13 EXACT (best measured: 389us).
// ---------------------------------------------------------------------------
#define REP8(M) M(0) M(1) M(2) M(3) M(4) M(5) M(6) M(7)
#define REP8G(M,G) M(G,0) M(G,1) M(G,2) M(G,3) M(G,4) M(G,5) M(G,6) M(G,7)

__global__ __launch_bounds__(512)
__attribute__((amdgpu_waves_per_eu(2, 2)))
void lstm_rec(
    const int* __restrict__ pad_seq, const int* __restrict__ lens,
    const float* __restrict__ Whh_f, const float* __restrict__ Whh_b,
    const float* __restrict__ embW, const float* __restrict__ W_lab,
    float* __restrict__ e_part) {
  const int dir = blockIdx.x & 1;
  const int b   = blockIdx.x >> 1;
  const int tid = threadIdx.x;
  const int j   = tid >> 2;      // hidden unit 0..127
  const int q   = tid & 3;       // K-quarter / gate owner 0..3
  const int parity = q & 1;
  const int half   = (q >> 1) & 1;

  __shared__ float ring[8][4][36];   // [slot][chunk][32 + 4 pad]
  __shared__ float wls[4][132];      // W_lab cols for MY direction, padded
  __shared__ int   tok[TMAX];

  tok[tid] = pad_seq[b * TMAX + tid];
  wls[tid >> 7][tid & 127] = W_lab[(tid >> 7) * DIM + dir * HID + (tid & 127)];
  if (tid < 144) ((float*)ring)[tid] = 0.f;    // slot 0 = h(-1) = 0

  const int len = lens[b];
  const float* __restrict__ Whh = dir ? Whh_b : Whh_f;

  const float4* wr0 = (const float4*)(Whh + (size_t)(0 * HID + j) * HID + 32 * q);
  const float4* wr1 = (const float4*)(Whh + (size_t)(1 * HID + j) * HID + 32 * q);
  const float4* wr2 = (const float4*)(Whh + (size_t)(2 * HID + j) * HID + 32 * q);
  const float4* wr3 = (const float4*)(Whh + (size_t)(3 * HID + j) * HID + 32 * q);
#define DECLW(G,I)                                                      \
  float w##G##_##I##_0, w##G##_##I##_1, w##G##_##I##_2, w##G##_##I##_3; \
  { float4 t = wr##G[I];                                                \
    w##G##_##I##_0 = t.x; w##G##_##I##_1 = t.y;                         \
    w##G##_##I##_2 = t.z; w##G##_##I##_3 = t.w; }                       \
  asm volatile("" : "+v"(w##G##_##I##_0));                              \
  asm volatile("" : "+v"(w##G##_##I##_1));                              \
  asm volatile("" : "+v"(w##G##_##I##_2));                              \
  asm volatile("" : "+v"(w##G##_##I##_3));
  REP8G(DECLW,0) REP8G(DECLW,1) REP8G(DECLW,2) REP8G(DECLW,3)
#undef DECLW

  float c = 0.f;
  const float ascale = (q == 2) ? 2.f : 1.f;     // tanh(x)=2*sig(2x)-1 for g
  const float* __restrict__ ecol = embW + dir * G4 + (q * HID + j);
  float* __restrict__ ep = e_part + (size_t)(dir * BATCH + b) * TMAX * 4;

  __syncthreads();

  float xb0, xb1, xb2, xb3, xb4, xb5, xb6, xb7;
  float yb0, yb1, yb2, yb3, yb4, yb5, yb6, yb7;
#define PREX(r) { const int ss = r; xb##r = 0.f;                        \
    if (ss < len) {                                                     \
      const int tt = dir ? (len - 1 - ss) : ss;                         \
      xb##r = ecol[(size_t)tok[tt] * NCOL]; } }
  REP8(PREX)
#undef PREX
#define PREY(r) { const int ss = nbase + r; yb##r = 0.f;                \
    if (ss < len) {                                                     \
      const int tt = dir ? (len - 1 - ss) : ss;                         \
      yb##r = ecol[(size_t)tok[tt] * NCOL]; } }

#define MACC(G,I)                                         \
    a##G##0 = fmaf(hv##I.x, w##G##_##I##_0, a##G##0);     \
    a##G##1 = fmaf(hv##I.y, w##G##_##I##_1, a##G##1);     \
    a##G##2 = fmaf(hv##I.z, w##G##_##I##_2, a##G##2);     \
    a##G##3 = fmaf(hv##I.w, w##G##_##I##_3, a##G##3);

#define STEP(r, XW)                                                     \
  {                                                                     \
    const float4* h4 = (const float4*)&ring[r][q][0];                   \
    float4 hv0 = h4[0], hv1 = h4[1], hv2 = h4[2], hv3 = h4[3];          \
    float4 hv4 = h4[4], hv5 = h4[5], hv6 = h4[6], hv7 = h4[7];          \
    float a00=0.f,a01=0.f,a02=0.f,a03=0.f;                              \
    float a10=0.f,a11=0.f,a12=0.f,a13=0.f;                              \
    float a20=0.f,a21=0.f,a22=0.f,a23=0.f;                              \
    float a30=0.f,a31=0.f,a32=0.f,a33=0.f;                              \
    REP8G(MACC,0) REP8G(MACC,1) REP8G(MACC,2) REP8G(MACC,3)             \
    const float p0 = (a00+a01)+(a02+a03);                               \
    const float p1 = (a10+a11)+(a12+a13);                               \
    const float p2 = (a20+a21)+(a22+a23);                               \
    const float p3 = (a30+a31)+(a32+a33);                               \
    const float klo = parity ? p1 : p0, slo = parity ? p0 : p1;         \
    const float khi = parity ? p3 : p2, shi = parity ? p2 : p3;         \
    const float alo = klo + dpp_xor1(slo);                              \
    const float ahi = khi + dpp_xor1(shi);                              \
    const float kb = half ? ahi : alo, sb = half ? alo : ahi;           \
    const float tot = kb + dpp_xor2(sb);                                \
    const float aa = tot + (XW);                                        \
    const float sg = 1.f / (1.f + __expf(-ascale * aa));                \
    const float act = (q == 2) ? (2.f * sg - 1.f) : sg;                 \
    const float e1 = dpp_xor1(act);                                     \
    const float e2 = dpp_xor2(act);                                     \
    const float e3 = dpp_xor2(e1);                                      \
    const float ev  = parity ? e1 : act, od  = parity ? act : e1;       \
    const float ev2 = parity ? e3 : e2,  od2 = parity ? e2 : e3;        \
    const float ig = half ? ev2 : ev, fg = half ? od2 : od;             \
    const float gt = half ? ev : ev2, og = half ? od : od2;             \
    c = fg * c + ig * gt;                                               \
    const float s2 = 1.f / (1.f + __expf(-2.f * c));                    \
    const float hh = og * (2.f * s2 - 1.f);                             \
    if (q == 0) ring[(r + 1) & 7][j >> 5][j & 31] = hh;                 \
    BARLDS();                                                           \
  }

  for (int s0 = 0; s0 < len; s0 += 8) {
    const int cnt = (len - s0 < 8) ? (len - s0) : 8;   // block-uniform
    STEP(0, xb0)
    if (cnt > 1) STEP(1, xb1)
    if (cnt > 2) STEP(2, xb2)
    if (cnt > 3) STEP(3, xb3)
    { const int nbase = s0 + 8; REP8(PREY) }
    if (cnt > 4) STEP(4, xb4)
    if (cnt > 5) STEP(5, xb5)
    if (cnt > 6) STEP(6, xb6)
    if (cnt > 7) STEP(7, xb7)
    {
      const int r = tid >> 6, l = (tid >> 4) & 3, sub = tid & 15;
      if (r < cnt) {
        const float4* hp = (const float4*)&ring[(r + 1) & 7][sub >> 2][8 * (sub & 3)];
        const float4 h0 = hp[0], h1 = hp[1];
        const float4* wp = (const float4*)&wls[l][8 * sub];
        const float4 u0 = wp[0], u1 = wp[1];
        float d = h0.x*u0.x + h0.y*u0.y + h0.z*u0.z + h0.w*u0.w
                + h1.x*u1.x + h1.y*u1.y + h1.z*u1.z + h1.w*u1.w;
        d += __shfl_xor(d, 1); d += __shfl_xor(d, 2);
        d += __shfl_xor(d, 4); d += __shfl_xor(d, 8);
        if (sub == 0) {
          const int ss = s0 + r;
          const int tt = dir ? (len - 1 - ss) : ss;
          ep[tt * 4 + l] = d;
        }
      }
    }
    BARLDS();
    xb0 = yb0; xb1 = yb1; xb2 = yb2; xb3 = yb3;
    xb4 = yb4; xb5 = yb5; xb6 = yb6; xb7 = yb7;
  }
#undef STEP
#undef MACC
#undef PREY
}

// ---------------------------------------------------------------------------
// Kernel 3: Viterbi -- R11 exact.
// ---------------------------------------------------------------------------
__global__ __launch_bounds__(512) void viterbi_k(
    const int* __restrict__ lens, const float* __restrict__ e_part,
    const float* __restrict__ b_lab, const float* __restrict__ trans,
    const float* __restrict__ from_BOS, const float* __restrict__ to_EOS,
    int* __restrict__ out) {
  const int b = blockIdx.x;
  const int tid = threadIdx.x;
  __shared__ float sc[TMAX][4];
  __shared__ unsigned btm[TMAX];
  __shared__ int labs[TMAX];
  const int len = lens[b];

  if (tid < len) {
    const float4 f  = *(const float4*)(e_part + ((size_t)b * TMAX + tid) * 4);
    const float4 g2 = *(const float4*)(e_part + ((size_t)(BATCH + b) * TMAX + tid) * 4);
    const float4 bl = *(const float4*)b_lab;
    sc[tid][0] = f.x + g2.x + bl.x;
    sc[tid][1] = f.y + g2.y + bl.y;
    sc[tid][2] = f.z + g2.z + bl.z;
    sc[tid][3] = f.w + g2.w + bl.w;
  }
  __syncthreads();

  if (tid < 4) {
    const int l = tid;
    float trc0 = trans[0 * 4 + l], trc1 = trans[1 * 4 + l];
    float trc2 = trans[2 * 4 + l], trc3 = trans[3 * 4 + l];
    float best = from_BOS[l] + sc[0][l];
    float eA = sc[1][l];
    float eB = sc[2][l];
    float eC = sc[3][l];
    for (int ti = 1; ti < len; ++ti) {
      const float e = eA;
      eA = eB; eB = eC;
      int nx = ti + 3; if (nx > TMAX - 1) nx = TMAX - 1;
      eC = sc[nx][l];
      const float b0 = dpp_bc0(best);
      const float b1 = dpp_bc1(best);
      const float b2 = dpp_bc2(best);
      const float b3 = dpp_bc3(best);
      float m = (b0 + e) + trc0; int arg = 0;
      float v;
      v = (b1 + e) + trc1; if (v > m) { m = v; arg = 1; }
      v = (b2 + e) + trc2; if (v > m) { m = v; arg = 2; }
      v = (b3 + e) + trc3; if (v > m) { m = v; arg = 3; }
      best = m;
      unsigned av = ((unsigned)arg) << (8 * l);
      av |= dpp_xor1u(av);
      av |= dpp_xor2u(av);
      if (l == 0) btm[ti] = av;
    }
    const float f0 = dpp_bc0(best) + to_EOS[0];
    const float f1 = dpp_bc1(best) + to_EOS[1];
    const float f2 = dpp_bc2(best) + to_EOS[2];
    const float f3 = dpp_bc3(best) + to_EOS[3];
    if (l == 0) {
      float m = f0; int last = 0;
      if (f1 > m) { m = f1; last = 1; }
      if (f2 > m) { m = f2; last = 2; }
      if (f3 > m) { m = f3; last = 3; }
      labs[len - 1] = last;
      int cur = last;
      int ti = len - 2;
      while (ti >= 0) {
        const int hi = ti + 1;
        const unsigned u0 = btm[hi];
        const unsigned u1 = (hi - 1 >= 1) ? btm[hi - 1] : 0u;
        const unsigned u2 = (hi - 2 >= 1) ? btm[hi - 2] : 0u;
        const unsigned u3 = (hi - 3 >= 1) ? btm[hi - 3] : 0u;
        const unsigned u4 = (hi - 4 >= 1) ? btm[hi - 4] : 0u;
        const unsigned u5 = (hi - 5 >= 1) ? btm[hi - 5] : 0u;
        const unsigned u6 = (hi - 6 >= 1) ? btm[hi - 6] : 0u;
        const unsigned u7 = (hi - 7 >= 1) ? btm[hi - 7] : 0u;
        cur = (int)((u0 >> (8 * cur)) & 255u); labs[ti--] = cur; if (ti < 0) break;
        cur = (int)((u1 >> (8 * cur)) & 255u); labs[ti--] = cur; if (ti < 0) break;
        cur = (int)((u2 >> (8 * cur)) & 255u); labs[ti--] = cur; if (ti < 0) break;
        cur = (int)((u3 >> (8 * cur)) & 255u); labs[ti--] = cur; if (ti < 0) break;
        cur = (int)((u4 >> (8 * cur)) & 255u); labs[ti--] = cur; if (ti < 0) break;
        cur = (int)((u5 >> (8 * cur)) & 255u); labs[ti--] = cur; if (ti < 0) break;
        cur = (int)((u6 >> (8 * cur)) & 255u); labs[ti--] = cur; if (ti < 0) break;
        cur = (int)((u7 >> (8 * cur)) & 255u); labs[ti--] = cur;
      }
    }
  }
  __syncthreads();
  out[b * TMAX + tid] = (tid < len) ? labs[tid] : 0;
}

// ---------------------------------------------------------------------------
extern "C" void kernel_launch(void* const* d_in, const int* in_sizes, int n_in,
                              void* d_out, int out_size, void* d_ws, size_t ws_size,
                              hipStream_t stream) {
  const int*   pad_seq  = (const int*)d_in[0];
  const int*   lens     = (const int*)d_in[1];
  const float* emb      = (const float*)d_in[2];
  const float* W_ih_f   = (const float*)d_in[3];
  const float* W_hh_f   = (const float*)d_in[4];
  const float* b_ih_f   = (const float*)d_in[5];
  const float* b_hh_f   = (const float*)d_in[6];
  const float* W_ih_b   = (const float*)d_in[7];
  const float* W_hh_b   = (const float*)d_in[8];
  const float* b_ih_b   = (const float*)d_in[9];
  const float* b_hh_b   = (const float*)d_in[10];
  const float* W_lab    = (const float*)d_in[11];
  const float* b_lab    = (const float*)d_in[12];
  const float* trans    = (const float*)d_in[13];
  const float* from_BOS = (const float*)d_in[14];
  const float* to_EOS   = (const float*)d_in[15];
  int* out = (int*)d_out;

  float* embW   = (float*)d_ws;                      // [8000][1024] = 32.8 MB
  float* e_part = embW + (size_t)VOCAB * NCOL;       // [2][B][T][4] = 2 MB

  embw_gemm<<<dim3(63, 8), 256, 0, stream>>>(emb, W_ih_f, W_ih_b,
                                             b_ih_f, b_hh_f, b_ih_b, b_hh_b, embW);
  lstm_rec<<<dim3(2 * BATCH), 512, 0, stream>>>(pad_seq, lens, W_hh_f, W_hh_b,
                                                embW, W_lab, e_part);
  viterbi_k<<<dim3(BATCH), 512, 0, stream>>>(lens, e_part, b_lab, trans,
                                             from_BOS, to_EOS, out);
}

// Round 15
// 581.930 us; speedup vs baseline: 8.6773x; 8.6773x over previous
//
#include <hip/hip_runtime.h>
#include <math.h>

#define VOCAB 8000
#define BATCH 128
#define TMAX  512
#define DIM   256
#define HID   128
#define G4    512     // 4*HID
#define NCOL  1024    // 2*G4 (both directions)

#define BARLDS() asm volatile("s_waitcnt lgkmcnt(0)\n\ts_barrier" ::: "memory")

// --- DPP quad-lane ops (R10: win over ds_bpermute __shfl) ---
__device__ __forceinline__ float dpp_xor1(float x) {   // [1,0,3,2] = 0xB1
  int r = __builtin_amdgcn_update_dpp(0, __builtin_bit_cast(int, x),
                                      0xB1, 0xF, 0xF, true);
  return __builtin_bit_cast(float, r);
}
__device__ __forceinline__ float dpp_xor2(float x) {   // [2,3,0,1] = 0x4E
  int r = __builtin_amdgcn_update_dpp(0, __builtin_bit_cast(int, x),
                                      0x4E, 0xF, 0xF, true);
  return __builtin_bit_cast(float, r);
}
__device__ __forceinline__ unsigned dpp_xor1u(unsigned x) {
  return (unsigned)__builtin_amdgcn_update_dpp(0, (int)x, 0xB1, 0xF, 0xF, true);
}
__device__ __forceinline__ unsigned dpp_xor2u(unsigned x) {
  return (unsigned)__builtin_amdgcn_update_dpp(0, (int)x, 0x4E, 0xF, 0xF, true);
}
__device__ __forceinline__ float dpp_bc0(float x) {
  int r = __builtin_amdgcn_update_dpp(0, __builtin_bit_cast(int, x),
                                      0x00, 0xF, 0xF, true);
  return __builtin_bit_cast(float, r);
}
__device__ __forceinline__ float dpp_bc1(float x) {
  int r = __builtin_amdgcn_update_dpp(0, __builtin_bit_cast(int, x),
                                      0x55, 0xF, 0xF, true);
  return __builtin_bit_cast(float, r);
}
__device__ __forceinline__ float dpp_bc2(float x) {
  int r = __builtin_amdgcn_update_dpp(0, __builtin_bit_cast(int, x),
                                      0xAA, 0xF, 0xF, true);
  return __builtin_bit_cast(float, r);
}
__device__ __forceinline__ float dpp_bc3(float x) {
  int r = __builtin_amdgcn_update_dpp(0, __builtin_bit_cast(int, x),
                                      0xFF, 0xF, 0xF, true);
  return __builtin_bit_cast(float, r);
}

// ---------------------------------------------------------------------------
// Kernel 1: embW[v][n] = emb[v,:] . W_ih_dir[n,:] + b_ih_dir[n] + b_hh_dir[n]
// R11-EXACT: 128x128 tile, 8x8 micro, single LDS buffer, register prefetch
// consumed at the TOP of the next iteration (keeps la/lb lifetimes short --
// R14's LDS double-buffer kept them live across the MAC loop: VGPR 256,
// scratch thrash, 4.5ms. R13's 8x16 micro: ~196 live regs, spill, +70us.)
// ---------------------------------------------------------------------------
__global__ __launch_bounds__(256) void embw_gemm(
    const float* __restrict__ emb,
    const float* __restrict__ Wf, const float* __restrict__ Wb,
    const float* __restrict__ bihf, const float* __restrict__ bhhf,
    const float* __restrict__ bihb, const float* __restrict__ bhhb,
    float* __restrict__ embW) {
  __shared__ float As[32][132];
  __shared__ float Bs[32][132];
  const int tid = threadIdx.x;
  const int m0 = blockIdx.x * 128;
  const int n0 = blockIdx.y * 128;
  const int tx = tid & 15, ty = tid >> 4;
  const int lrow = tid >> 1;
  const int lseg = (tid & 1) * 16;
  const float* Wsrc = (n0 < 512) ? Wf : Wb;
  const int nbase = (n0 < 512) ? n0 : (n0 - 512);
  const int gm = m0 + lrow;

  float acc[8][8];
  #pragma unroll
  for (int i = 0; i < 8; ++i)
    #pragma unroll
    for (int jj = 0; jj < 8; ++jj) acc[i][jj] = 0.f;

  float4 la[4], lb[4];
#define LOADT(K0)                                                         \
  { _Pragma("unroll")                                                     \
    for (int qq = 0; qq < 4; ++qq) {                                      \
      la[qq] = make_float4(0.f, 0.f, 0.f, 0.f);                           \
      if (gm < VOCAB)                                                     \
        la[qq] = *(const float4*)(emb + (size_t)gm * 256 + (K0) + lseg + 4 * qq); \
      lb[qq] = *(const float4*)(Wsrc + (size_t)(nbase + lrow) * 256 + (K0) + lseg + 4 * qq); \
    } }

  LOADT(0)
  for (int k0 = 0; k0 < 256; k0 += 32) {
    #pragma unroll
    for (int qq = 0; qq < 4; ++qq) {
      As[lseg + 4*qq + 0][lrow] = la[qq].x;
      As[lseg + 4*qq + 1][lrow] = la[qq].y;
      As[lseg + 4*qq + 2][lrow] = la[qq].z;
      As[lseg + 4*qq + 3][lrow] = la[qq].w;
      Bs[lseg + 4*qq + 0][lrow] = lb[qq].x;
      Bs[lseg + 4*qq + 1][lrow] = lb[qq].y;
      Bs[lseg + 4*qq + 2][lrow] = lb[qq].z;
      Bs[lseg + 4*qq + 3][lrow] = lb[qq].w;
    }
    __syncthreads();
    if (k0 + 32 < 256) LOADT(k0 + 32)
    #pragma unroll
    for (int k = 0; k < 32; ++k) {
      float4 av0 = *(const float4*)&As[k][ty * 8];
      float4 av1 = *(const float4*)&As[k][ty * 8 + 4];
      float4 bv0 = *(const float4*)&Bs[k][tx * 4];
      float4 bv1 = *(const float4*)&Bs[k][64 + tx * 4];
      float a[8]  = {av0.x, av0.y, av0.z, av0.w, av1.x, av1.y, av1.z, av1.w};
      float bb[8] = {bv0.x, bv0.y, bv0.z, bv0.w, bv1.x, bv1.y, bv1.z, bv1.w};
      #pragma unroll
      for (int i = 0; i < 8; ++i)
        #pragma unroll
        for (int jj = 0; jj < 8; ++jj)
          acc[i][jj] += a[i] * bb[jj];
    }
    __syncthreads();
  }
#undef LOADT

  float bias[8];
  #pragma unroll
  for (int jj = 0; jj < 8; ++jj) {
    int n = n0 + ((jj < 4) ? (tx * 4 + jj) : (64 + tx * 4 + (jj - 4)));
    bias[jj] = (n < 512) ? (bihf[n] + bhhf[n]) : (bihb[n - 512] + bhhb[n - 512]);
  }
  #pragma unroll
  for (int i = 0; i < 8; ++i) {
    int gmo = m0 + ty * 8 + i;
    if (gmo >= VOCAB) continue;
    float4 v0 = make_float4(acc[i][0] + bias[0], acc[i][1] + bias[1],
                            acc[i][2] + bias[2], acc[i][3] + bias[3]);
    float4 v1 = make_float4(acc[i][4] + bias[4], acc[i][5] + bias[5],
                            acc[i][6] + bias[6], acc[i][7] + bias[7]);
    *(float4*)(embW + (size_t)gmo * NCOL + n0 + tx * 4) = v0;
    *(float4*)(embW + (size_t)gmo * NCOL + n0 + 64 + tx * 4) = v1;
  }
}

// ---------------------------------------------------------------------------
// Kernel 2: masked LSTM recurrence -- R13 EXACT (best measured: 389us).
// ---------------------------------------------------------------------------
#define REP8(M) M(0) M(1) M(2) M(3) M(4) M(5) M(6) M(7)
#define REP8G(M,G) M(G,0) M(G,1) M(G,2) M(G,3) M(G,4) M(G,5) M(G,6) M(G,7)

__global__ __launch_bounds__(512)
__attribute__((amdgpu_waves_per_eu(2, 2)))
void lstm_rec(
    const int* __restrict__ pad_seq, const int* __restrict__ lens,
    const float* __restrict__ Whh_f, const float* __restrict__ Whh_b,
    const float* __restrict__ embW, const float* __restrict__ W_lab,
    float* __restrict__ e_part) {
  const int dir = blockIdx.x & 1;
  const int b   = blockIdx.x >> 1;
  const int tid = threadIdx.x;
  const int j   = tid >> 2;      // hidden unit 0..127
  const int q   = tid & 3;       // K-quarter / gate owner 0..3
  const int parity = q & 1;
  const int half   = (q >> 1) & 1;

  __shared__ float ring[8][4][36];   // [slot][chunk][32 + 4 pad]
  __shared__ float wls[4][132];      // W_lab cols for MY direction, padded
  __shared__ int   tok[TMAX];

  tok[tid] = pad_seq[b * TMAX + tid];
  wls[tid >> 7][tid & 127] = W_lab[(tid >> 7) * DIM + dir * HID + (tid & 127)];
  if (tid < 144) ((float*)ring)[tid] = 0.f;    // slot 0 = h(-1) = 0

  const int len = lens[b];
  const float* __restrict__ Whh = dir ? Whh_b : Whh_f;

  const float4* wr0 = (const float4*)(Whh + (size_t)(0 * HID + j) * HID + 32 * q);
  const float4* wr1 = (const float4*)(Whh + (size_t)(1 * HID + j) * HID + 32 * q);
  const float4* wr2 = (const float4*)(Whh + (size_t)(2 * HID + j) * HID + 32 * q);
  const float4* wr3 = (const float4*)(Whh + (size_t)(3 * HID + j) * HID + 32 * q);
#define DECLW(G,I)                                                      \
  float w##G##_##I##_0, w##G##_##I##_1, w##G##_##I##_2, w##G##_##I##_3; \
  { float4 t = wr##G[I];                                                \
    w##G##_##I##_0 = t.x; w##G##_##I##_1 = t.y;                         \
    w##G##_##I##_2 = t.z; w##G##_##I##_3 = t.w; }                       \
  asm volatile("" : "+v"(w##G##_##I##_0));                              \
  asm volatile("" : "+v"(w##G##_##I##_1));                              \
  asm volatile("" : "+v"(w##G##_##I##_2));                              \
  asm volatile("" : "+v"(w##G##_##I##_3));
  REP8G(DECLW,0) REP8G(DECLW,1) REP8G(DECLW,2) REP8G(DECLW,3)
#undef DECLW

  float c = 0.f;
  const float ascale = (q == 2) ? 2.f : 1.f;     // tanh(x)=2*sig(2x)-1 for g
  const float* __restrict__ ecol = embW + dir * G4 + (q * HID + j);
  float* __restrict__ ep = e_part + (size_t)(dir * BATCH + b) * TMAX * 4;

  __syncthreads();

  float xb0, xb1, xb2, xb3, xb4, xb5, xb6, xb7;
  float yb0, yb1, yb2, yb3, yb4, yb5, yb6, yb7;
#define PREX(r) { const int ss = r; xb##r = 0.f;                        \
    if (ss < len) {                                                     \
      const int tt = dir ? (len - 1 - ss) : ss;                         \
      xb##r = ecol[(size_t)tok[tt] * NCOL]; } }
  REP8(PREX)
#undef PREX
#define PREY(r) { const int ss = nbase + r; yb##r = 0.f;                \
    if (ss < len) {                                                     \
      const int tt = dir ? (len - 1 - ss) : ss;                         \
      yb##r = ecol[(size_t)tok[tt] * NCOL]; } }

#define MACC(G,I)                                         \
    a##G##0 = fmaf(hv##I.x, w##G##_##I##_0, a##G##0);     \
    a##G##1 = fmaf(hv##I.y, w##G##_##I##_1, a##G##1);     \
    a##G##2 = fmaf(hv##I.z, w##G##_##I##_2, a##G##2);     \
    a##G##3 = fmaf(hv##I.w, w##G##_##I##_3, a##G##3);

#define STEP(r, XW)                                                     \
  {                                                                     \
    const float4* h4 = (const float4*)&ring[r][q][0];                   \
    float4 hv0 = h4[0], hv1 = h4[1], hv2 = h4[2], hv3 = h4[3];          \
    float4 hv4 = h4[4], hv5 = h4[5], hv6 = h4[6], hv7 = h4[7];          \
    float a00=0.f,a01=0.f,a02=0.f,a03=0.f;                              \
    float a10=0.f,a11=0.f,a12=0.f,a13=0.f;                              \
    float a20=0.f,a21=0.f,a22=0.f,a23=0.f;                              \
    float a30=0.f,a31=0.f,a32=0.f,a33=0.f;                              \
    REP8G(MACC,0) REP8G(MACC,1) REP8G(MACC,2) REP8G(MACC,3)             \
    const float p0 = (a00+a01)+(a02+a03);                               \
    const float p1 = (a10+a11)+(a12+a13);                               \
    const float p2 = (a20+a21)+(a22+a23);                               \
    const float p3 = (a30+a31)+(a32+a33);                               \
    const float klo = parity ? p1 : p0, slo = parity ? p0 : p1;         \
    const float khi = parity ? p3 : p2, shi = parity ? p2 : p3;         \
    const float alo = klo + dpp_xor1(slo);                              \
    const float ahi = khi + dpp_xor1(shi);                              \
    const float kb = half ? ahi : alo, sb = half ? alo : ahi;           \
    const float tot = kb + dpp_xor2(sb);                                \
    const float aa = tot + (XW);                                        \
    const float sg = 1.f / (1.f + __expf(-ascale * aa));                \
    const float act = (q == 2) ? (2.f * sg - 1.f) : sg;                 \
    const float e1 = dpp_xor1(act);                                     \
    const float e2 = dpp_xor2(act);                                     \
    const float e3 = dpp_xor2(e1);                                      \
    const float ev  = parity ? e1 : act, od  = parity ? act : e1;       \
    const float ev2 = parity ? e3 : e2,  od2 = parity ? e2 : e3;        \
    const float ig = half ? ev2 : ev, fg = half ? od2 : od;             \
    const float gt = half ? ev : ev2, og = half ? od : od2;             \
    c = fg * c + ig * gt;                                               \
    const float s2 = 1.f / (1.f + __expf(-2.f * c));                    \
    const float hh = og * (2.f * s2 - 1.f);                             \
    if (q == 0) ring[(r + 1) & 7][j >> 5][j & 31] = hh;                 \
    BARLDS();                                                           \
  }

  for (int s0 = 0; s0 < len; s0 += 8) {
    const int cnt = (len - s0 < 8) ? (len - s0) : 8;   // block-uniform
    STEP(0, xb0)
    if (cnt > 1) STEP(1, xb1)
    if (cnt > 2) STEP(2, xb2)
    if (cnt > 3) STEP(3, xb3)
    { const int nbase = s0 + 8; REP8(PREY) }
    if (cnt > 4) STEP(4, xb4)
    if (cnt > 5) STEP(5, xb5)
    if (cnt > 6) STEP(6, xb6)
    if (cnt > 7) STEP(7, xb7)
    {
      const int r = tid >> 6, l = (tid >> 4) & 3, sub = tid & 15;
      if (r < cnt) {
        const float4* hp = (const float4*)&ring[(r + 1) & 7][sub >> 2][8 * (sub & 3)];
        const float4 h0 = hp[0], h1 = hp[1];
        const float4* wp = (const float4*)&wls[l][8 * sub];
        const float4 u0 = wp[0], u1 = wp[1];
        float d = h0.x*u0.x + h0.y*u0.y + h0.z*u0.z + h0.w*u0.w
                + h1.x*u1.x + h1.y*u1.y + h1.z*u1.z + h1.w*u1.w;
        d += __shfl_xor(d, 1); d += __shfl_xor(d, 2);
        d += __shfl_xor(d, 4); d += __shfl_xor(d, 8);
        if (sub == 0) {
          const int ss = s0 + r;
          const int tt = dir ? (len - 1 - ss) : ss;
          ep[tt * 4 + l] = d;
        }
      }
    }
    BARLDS();
    xb0 = yb0; xb1 = yb1; xb2 = yb2; xb3 = yb3;
    xb4 = yb4; xb5 = yb5; xb6 = yb6; xb7 = yb7;
  }
#undef STEP
#undef MACC
#undef PREY
}

// ---------------------------------------------------------------------------
// Kernel 3: Viterbi -- R11 exact.
// ---------------------------------------------------------------------------
__global__ __launch_bounds__(512) void viterbi_k(
    const int* __restrict__ lens, const float* __restrict__ e_part,
    const float* __restrict__ b_lab, const float* __restrict__ trans,
    const float* __restrict__ from_BOS, const float* __restrict__ to_EOS,
    int* __restrict__ out) {
  const int b = blockIdx.x;
  const int tid = threadIdx.x;
  __shared__ float sc[TMAX][4];
  __shared__ unsigned btm[TMAX];
  __shared__ int labs[TMAX];
  const int len = lens[b];

  if (tid < len) {
    const float4 f  = *(const float4*)(e_part + ((size_t)b * TMAX + tid) * 4);
    const float4 g2 = *(const float4*)(e_part + ((size_t)(BATCH + b) * TMAX + tid) * 4);
    const float4 bl = *(const float4*)b_lab;
    sc[tid][0] = f.x + g2.x + bl.x;
    sc[tid][1] = f.y + g2.y + bl.y;
    sc[tid][2] = f.z + g2.z + bl.z;
    sc[tid][3] = f.w + g2.w + bl.w;
  }
  __syncthreads();

  if (tid < 4) {
    const int l = tid;
    float trc0 = trans[0 * 4 + l], trc1 = trans[1 * 4 + l];
    float trc2 = trans[2 * 4 + l], trc3 = trans[3 * 4 + l];
    float best = from_BOS[l] + sc[0][l];
    float eA = sc[1][l];
    float eB = sc[2][l];
    float eC = sc[3][l];
    for (int ti = 1; ti < len; ++ti) {
      const float e = eA;
      eA = eB; eB = eC;
      int nx = ti + 3; if (nx > TMAX - 1) nx = TMAX - 1;
      eC = sc[nx][l];
      const float b0 = dpp_bc0(best);
      const float b1 = dpp_bc1(best);
      const float b2 = dpp_bc2(best);
      const float b3 = dpp_bc3(best);
      float m = (b0 + e) + trc0; int arg = 0;
      float v;
      v = (b1 + e) + trc1; if (v > m) { m = v; arg = 1; }
      v = (b2 + e) + trc2; if (v > m) { m = v; arg = 2; }
      v = (b3 + e) + trc3; if (v > m) { m = v; arg = 3; }
      best = m;
      unsigned av = ((unsigned)arg) << (8 * l);
      av |= dpp_xor1u(av);
      av |= dpp_xor2u(av);
      if (l == 0) btm[ti] = av;
    }
    const float f0 = dpp_bc0(best) + to_EOS[0];
    const float f1 = dpp_bc1(best) + to_EOS[1];
    const float f2 = dpp_bc2(best) + to_EOS[2];
    const float f3 = dpp_bc3(best) + to_EOS[3];
    if (l == 0) {
      float m = f0; int last = 0;
      if (f1 > m) { m = f1; last = 1; }
      if (f2 > m) { m = f2; last = 2; }
      if (f3 > m) { m = f3; last = 3; }
      labs[len - 1] = last;
      int cur = last;
      int ti = len - 2;
      while (ti >= 0) {
        const int hi = ti + 1;
        const unsigned u0 = btm[hi];
        const unsigned u1 = (hi - 1 >= 1) ? btm[hi - 1] : 0u;
        const unsigned u2 = (hi - 2 >= 1) ? btm[hi - 2] : 0u;
        const unsigned u3 = (hi - 3 >= 1) ? btm[hi - 3] : 0u;
        const unsigned u4 = (hi - 4 >= 1) ? btm[hi - 4] : 0u;
        const unsigned u5 = (hi - 5 >= 1) ? btm[hi - 5] : 0u;
        const unsigned u6 = (hi - 6 >= 1) ? btm[hi - 6] : 0u;
        const unsigned u7 = (hi - 7 >= 1) ? btm[hi - 7] : 0u;
        cur = (int)((u0 >> (8 * cur)) & 255u); labs[ti--] = cur; if (ti < 0) break;
        cur = (int)((u1 >> (8 * cur)) & 255u); labs[ti--] = cur; if (ti < 0) break;
        cur = (int)((u2 >> (8 * cur)) & 255u); labs[ti--] = cur; if (ti < 0) break;
        cur = (int)((u3 >> (8 * cur)) & 255u); labs[ti--] = cur; if (ti < 0) break;
        cur = (int)((u4 >> (8 * cur)) & 255u); labs[ti--] = cur; if (ti < 0) break;
        cur = (int)((u5 >> (8 * cur)) & 255u); labs[ti--] = cur; if (ti < 0) break;
        cur = (int)((u6 >> (8 * cur)) & 255u); labs[ti--] = cur; if (ti < 0) break;
        cur = (int)((u7 >> (8 * cur)) & 255u); labs[ti--] = cur;
      }
    }
  }
  __syncthreads();
  out[b * TMAX + tid] = (tid < len) ? labs[tid] : 0;
}

// ---------------------------------------------------------------------------
extern "C" void kernel_launch(void* const* d_in, const int* in_sizes, int n_in,
                              void* d_out, int out_size, void* d_ws, size_t ws_size,
                              hipStream_t stream) {
  const int*   pad_seq  = (const int*)d_in[0];
  const int*   lens     = (const int*)d_in[1];
  const float* emb      = (const float*)d_in[2];
  const float* W_ih_f   = (const float*)d_in[3];
  const float* W_hh_f   = (const float*)d_in[4];
  const float* b_ih_f   = (const float*)d_in[5];
  const float* b_hh_f   = (const float*)d_in[6];
  const float* W_ih_b   = (const float*)d_in[7];
  const float* W_hh_b   = (const float*)d_in[8];
  const float* b_ih_b   = (const float*)d_in[9];
  const float* b_hh_b   = (const float*)d_in[10];
  const float* W_lab    = (const float*)d_in[11];
  const float* b_lab    = (const float*)d_in[12];
  const float* trans    = (const float*)d_in[13];
  const float* from_BOS = (const float*)d_in[14];
  const float* to_EOS   = (const float*)d_in[15];
  int* out = (int*)d_out;

  float* embW   = (float*)d_ws;                      // [8000][1024] = 32.8 MB
  float* e_part = embW + (size_t)VOCAB * NCOL;       // [2][B][T][4] = 2 MB

  embw_gemm<<<dim3(63, 8), 256, 0, stream>>>(emb, W_ih_f, W_ih_b,
                                             b_ih_f, b_hh_f, b_ih_b, b_hh_b, embW);
  lstm_rec<<<dim3(2 * BATCH), 512, 0, stream>>>(pad_seq, lens, W_hh_f, W_hh_b,
                                                embW, W_lab, e_part);
  viterbi_k<<<dim3(BATCH), 512, 0, stream>>>(lens, e_part, b_lab, trans,
                                             from_BOS, to_EOS, out);
}